// Round 9
// baseline (318.839 us; speedup 1.0000x reference)
//
#include <hip/hip_runtime.h>

// ConsMaxAttention MI355X — ROUND 9: conflict-free attention + async GEMMs.
// r8 (318 us): attn bank conflicts (V-transpose scalar stores, 16-row stride
// aliasing mod 32 banks) + P scatter; GEMMs at ~215 TF (fp32 cvt in staging).
// Changes: (1) qkv_gemm writes V^T [B,NH,HD,S] (epilogue-free transpose);
// (2) attention computes S^T = K·Q^T so P lands key-contiguous -> b64 writes,
// b128 reads, 2-shuffle row-max, lane-local exp shift; (3) weights
// pre-converted to bf16, GEMM B/A staged via global_load_lds width=16.
// ws 30 MB: q|k|vT 24 MB + Wcat3 6 MB; ctx0 aliases Wq/Wk_bf (dead after
// qkv), ctx1 aliases q-batch0 (dead after attn b0; attn launches serial).

typedef unsigned short u16;
typedef __attribute__((ext_vector_type(8))) short short8;
typedef __attribute__((ext_vector_type(4))) float floatx4;

constexpr int B_  = 2;
constexpr int S_  = 2048;
constexpr int HID = 1024;
constexpr int NH  = 16;
constexpr int HD  = 64;
constexpr int M_  = B_ * S_;   // 4096

__device__ __forceinline__ float us2f(u16 u) {
    union { unsigned int i; float f; } x;
    x.i = ((unsigned int)u) << 16;
    return x.f;
}
__device__ __forceinline__ u16 f2us(float f) {
    union { float f; unsigned int i; } x;
    x.f = f;
    unsigned int r = x.i + 0x7FFFu + ((x.i >> 16) & 1u);  // RNE
    return (u16)(r >> 16);
}
__device__ __forceinline__ void async_lds16(const u16* g, u16* l) {
    __builtin_amdgcn_global_load_lds(
        (const __attribute__((address_space(1))) unsigned int*)g,
        (__attribute__((address_space(3))) unsigned int*)l, 16, 0, 0);
}

// ---------------------------------------------------------------------------
// Convert Wq/Wk/Wv fp32 -> bf16 concatenated [3][1024][1024].
__global__ __launch_bounds__(256)
void cvt_w(const float* __restrict__ Wq, const float* __restrict__ Wk,
           const float* __restrict__ Wv, u16* __restrict__ Wcat)
{
    const float* W = (blockIdx.y == 0) ? Wq : (blockIdx.y == 1) ? Wk : Wv;
    const int i = (blockIdx.x * 256 + threadIdx.x) * 4;
    float4 t = *(const float4*)(W + i);
    ushort4 o = { f2us(t.x), f2us(t.y), f2us(t.z), f2us(t.w) };
    *(ushort4*)(Wcat + (size_t)blockIdx.y * 1048576 + i) = o;
}

// ---------------------------------------------------------------------------
// QKV GEMM: A = hs fp32 (VALU cvt), B = Wcat bf16 (async frag-order stage).
// p==2 writes V^T [B,NH,HD,S] with vectorized epilogue.
__global__ __launch_bounds__(256)
void qkv_gemm(const float* __restrict__ hs, const u16* __restrict__ Wcat,
              const float* __restrict__ bq, const float* __restrict__ bk,
              const float* __restrict__ bv,
              u16* __restrict__ Qo, u16* __restrict__ Ko, u16* __restrict__ VT)
{
    __shared__ u16 Alds[4096];
    __shared__ u16 Blds[4096];

    const int tid = threadIdx.x;
    const int m0  = blockIdx.x * 128;
    const int n0g = blockIdx.y * 128;
    const int p   = n0g >> 10;
    const int n0  = n0g & 1023;
    const u16*   Wb = Wcat + (size_t)p * 1048576;
    const float* bi = (p == 0) ? bq : (p == 1) ? bk : bv;

    const int w = tid >> 6, l = tid & 63;
    const int wy = w >> 1, wx = w & 1;
    const int r  = tid >> 1;
    const int hh = tid & 1;

    floatx4 acc[4][4];
    #pragma unroll
    for (int i = 0; i < 4; ++i)
        #pragma unroll
        for (int j = 0; j < 4; ++j) acc[i][j] = (floatx4){0.f, 0.f, 0.f, 0.f};

    for (int k0 = 0; k0 < HID; k0 += 32) {
        const float* Ap = hs + (size_t)(m0 + r) * HID + k0 + 16 * hh;
        float af[16];
        #pragma unroll
        for (int c = 0; c < 4; ++c) {
            float4 t = *(const float4*)(Ap + 4 * c);
            af[4*c] = t.x; af[4*c+1] = t.y; af[4*c+2] = t.z; af[4*c+3] = t.w;
        }
        __syncthreads();                      // prev mfma done reading LDS
        #pragma unroll
        for (int c = 0; c < 2; ++c) {         // async B: wave w -> blocks 2w+c
            const int s = w * 2 + c;
            async_lds16(Wb + (size_t)(n0 + s * 16 + (l & 15)) * HID + k0 + (l >> 4) * 8,
                        &Blds[s * 512]);
        }
        #pragma unroll
        for (int c2 = 0; c2 < 2; ++c2) {      // A frag-order writes
            const int quad  = 2 * hh + c2;
            const int lane8 = (r & 15) + 16 * quad;
            u16 ta[8];
            #pragma unroll
            for (int j = 0; j < 8; ++j) ta[j] = f2us(af[8*c2 + j]);
            *(short8*)&Alds[(r >> 4) * 512 + lane8 * 8] = *(short8*)ta;
        }
        __syncthreads();

        short8 afr[4], bfr[4];
        #pragma unroll
        for (int i = 0; i < 4; ++i) afr[i] = *(const short8*)&Alds[(wy*4 + i) * 512 + l * 8];
        #pragma unroll
        for (int j = 0; j < 4; ++j) bfr[j] = *(const short8*)&Blds[(wx*4 + j) * 512 + l * 8];
        #pragma unroll
        for (int i = 0; i < 4; ++i)
            #pragma unroll
            for (int j = 0; j < 4; ++j)
                acc[i][j] = __builtin_amdgcn_mfma_f32_16x16x32_bf16(afr[i], bfr[j], acc[i][j], 0, 0, 0);
    }

    #pragma unroll
    for (int i = 0; i < 4; ++i)
        #pragma unroll
        for (int j = 0; j < 4; ++j) {
            const int nn   = n0 + wx * 64 + j * 16 + (l & 15);
            const int head = nn >> 6, dd = nn & 63;
            const float bb_ = bi[nn];
            const int mmb = m0 + wy * 64 + i * 16 + (l >> 4) * 4;
            const int b = mmb >> 11, ss = mmb & (S_ - 1);
            if (p == 2) {                     // V^T: 4 contiguous s -> ushort4
                ushort4 st;
                st.x = f2us(acc[i][j][0] + bb_);
                st.y = f2us(acc[i][j][1] + bb_);
                st.z = f2us(acc[i][j][2] + bb_);
                st.w = f2us(acc[i][j][3] + bb_);
                *(ushort4*)(VT + (((size_t)(b * NH + head)) * HD + dd) * S_ + ss) = st;
            } else {
                u16* Out = (p == 0) ? Qo : Ko;
                #pragma unroll
                for (int rg = 0; rg < 4; ++rg)
                    Out[(((size_t)b * NH + head) * S_ + ss + rg) * HD + dd] =
                        f2us(acc[i][j][rg] + bb_);
            }
        }
}

// ---------------------------------------------------------------------------
// Flash ConsMax attention, S^T formulation. One batch per launch.
// 64 q/block (16 per wave), 64-key tiles. All LDS traffic b64/b128.
__global__ __launch_bounds__(256)
void attn2(const u16* __restrict__ Qg, const u16* __restrict__ Kg,
           const u16* __restrict__ VTg, const float* __restrict__ mask,
           const float* __restrict__ gamma, u16* __restrict__ ctx, int b0)
{
    __shared__ u16 Klds[64][72];      // [key][d]
    __shared__ u16 Vt[64][72];        // [d][key]  (from global V^T, no transpose)
    __shared__ u16 Plds[4][16 * 72];  // per-wave [q][key], stride 72
    __shared__ float maskadd[64];

    const int tid = threadIdx.x;
    const int w = tid >> 6, l = tid & 63;
    const int quad = l >> 4, l16 = l & 15;
    const int qb = blockIdx.x;
    const int h  = blockIdx.y;
    const int bh = b0 * NH + h;

    const u16* Qb = Qg  + (size_t)bh * S_ * HD;
    const u16* Kb = Kg  + (size_t)bh * S_ * HD;
    const u16* Vb = VTg + (size_t)bh * HD * S_;

    short8 qf[2];                     // Q[q = qb*64+16w+l16][32t+quad*8 ..]
    #pragma unroll
    for (int t = 0; t < 2; ++t)
        qf[t] = *(const short8*)(Qb + ((size_t)qb * 64 + 16 * w + l16) * HD + 32 * t + quad * 8);

    floatx4 o_acc[4];
    #pragma unroll
    for (int jn = 0; jn < 4; ++jn) o_acc[jn] = (floatx4){0.f, 0.f, 0.f, 0.f};
    float m_run = -1e30f;             // per-lane online max, q = l16

    const int r = tid >> 2;           // staging row (key for K, d for V^T)
    const int c = (tid & 3) * 16;

    for (int kt = 0; kt < S_ / 64; ++kt) {
        const u16* Kp = Kb + ((size_t)kt * 64 + r) * HD + c;
        const u16* Vp = Vb + (size_t)r * S_ + kt * 64 + c;
        uint4 k0v = *(const uint4*)Kp, k1v = *(const uint4*)(Kp + 8);
        uint4 v0v = *(const uint4*)Vp, v1v = *(const uint4*)(Vp + 8);
        float ma = 0.0f;
        if (tid < 64) ma = (1.0f - mask[(size_t)b0 * S_ + kt * 64 + tid]) * -10000.0f;
        __syncthreads();
        *(short8*)&Klds[r][c]     = *(const short8*)&k0v;
        *(short8*)&Klds[r][c + 8] = *(const short8*)&k1v;
        *(short8*)&Vt[r][c]       = *(const short8*)&v0v;
        *(short8*)&Vt[r][c + 8]   = *(const short8*)&v1v;
        if (tid < 64) maskadd[tid] = ma;
        __syncthreads();

        // S^T = K·Q^T : D[m=key][n=q], lane: keys j*16+quad*4+i, q=l16
        floatx4 st4[4];
        #pragma unroll
        for (int j = 0; j < 4; ++j) st4[j] = (floatx4){0.f, 0.f, 0.f, 0.f};
        #pragma unroll
        for (int t = 0; t < 2; ++t)
            #pragma unroll
            for (int j = 0; j < 4; ++j) {
                short8 kf = *(const short8*)&Klds[j * 16 + l16][32 * t + quad * 8];
                st4[j] = __builtin_amdgcn_mfma_f32_16x16x32_bf16(kf, qf[t], st4[j], 0, 0, 0);
            }

        float sv[4][4], mx = -1e30f;
        #pragma unroll
        for (int j = 0; j < 4; ++j)
            #pragma unroll
            for (int i = 0; i < 4; ++i) {
                const float s = st4[j][i] * 0.125f + maskadd[j * 16 + quad * 4 + i];
                sv[j][i] = s;
                mx = fmaxf(mx, s);
            }
        mx = fmaxf(mx, __shfl_xor(mx, 16, 64));   // reduce across quads
        mx = fmaxf(mx, __shfl_xor(mx, 32, 64));

        const float nm  = fmaxf(m_run, mx);
        const float scl = __expf(m_run - nm);
        m_run = nm;

        // P -> wave-private LDS [q][key], 4 contiguous keys per b64 write
        #pragma unroll
        for (int j = 0; j < 4; ++j) {
            ushort4 pp;
            pp.x = f2us(__expf(sv[j][0] - nm));
            pp.y = f2us(__expf(sv[j][1] - nm));
            pp.z = f2us(__expf(sv[j][2] - nm));
            pp.w = f2us(__expf(sv[j][3] - nm));
            *(ushort4*)&Plds[w][l16 * 72 + j * 16 + quad * 4] = pp;
        }

        // rescale O (rows q = quad*4+i need lane quad*4+i's scale)
        #pragma unroll
        for (int i = 0; i < 4; ++i) {
            const float si = __shfl(scl, quad * 4 + i, 64);
            #pragma unroll
            for (int jn = 0; jn < 4; ++jn) o_acc[jn][i] *= si;
        }

        // O += P·V : A = P (rows q=l16), B = V (from Vt[d][key])
        #pragma unroll
        for (int t = 0; t < 2; ++t) {
            short8 pf = *(const short8*)&Plds[w][l16 * 72 + 32 * t + quad * 8];
            #pragma unroll
            for (int jn = 0; jn < 4; ++jn) {
                short8 vf = *(const short8*)&Vt[jn * 16 + l16][32 * t + quad * 8];
                o_acc[jn] = __builtin_amdgcn_mfma_f32_16x16x32_bf16(pf, vf, o_acc[jn], 0, 0, 0);
            }
        }
    }

    const float ig = 1.0f / gamma[0];
    #pragma unroll
    for (int jn = 0; jn < 4; ++jn)
        #pragma unroll
        for (int i = 0; i < 4; ++i) {
            const int srow = qb * 64 + 16 * w + quad * 4 + i;
            ctx[(size_t)srow * HID + h * HD + jn * 16 + l16] = f2us(o_acc[jn][i] * ig);
        }
}

// ---------------------------------------------------------------------------
// Output GEMM: A = ctx bf16 (async stage), B = Wo fp32 (VALU cvt), fp32 out.
__global__ __launch_bounds__(256)
void out_gemm(const u16* __restrict__ ctx0, const u16* __restrict__ ctx1,
              const float* __restrict__ Wo, const float* __restrict__ bo,
              float* __restrict__ out)
{
    __shared__ u16 Alds[4096];
    __shared__ u16 Blds[4096];

    const int tid = threadIdx.x;
    const int m0 = blockIdx.x * 128;
    const int n0 = blockIdx.y * 128;
    const u16* ctxp = (m0 < S_) ? ctx0 : ctx1;
    const int mr0 = m0 & (S_ - 1);

    const int w = tid >> 6, l = tid & 63;
    const int wy = w >> 1, wx = w & 1;
    const int r  = tid >> 1;
    const int hh = tid & 1;

    floatx4 acc[4][4];
    #pragma unroll
    for (int i = 0; i < 4; ++i)
        #pragma unroll
        for (int j = 0; j < 4; ++j) acc[i][j] = (floatx4){0.f, 0.f, 0.f, 0.f};

    for (int k0 = 0; k0 < HID; k0 += 32) {
        const float* Bp = Wo + (size_t)(n0 + r) * HID + k0 + 16 * hh;
        float bf[16];
        #pragma unroll
        for (int c = 0; c < 4; ++c) {
            float4 u = *(const float4*)(Bp + 4 * c);
            bf[4*c] = u.x; bf[4*c+1] = u.y; bf[4*c+2] = u.z; bf[4*c+3] = u.w;
        }
        __syncthreads();
        #pragma unroll
        for (int c = 0; c < 2; ++c) {         // async A: wave w -> blocks 2w+c
            const int s = w * 2 + c;
            async_lds16(ctxp + (size_t)(mr0 + s * 16 + (l & 15)) * HID + k0 + (l >> 4) * 8,
                        &Alds[s * 512]);
        }
        #pragma unroll
        for (int c2 = 0; c2 < 2; ++c2) {      // B frag-order writes
            const int quad  = 2 * hh + c2;
            const int lane8 = (r & 15) + 16 * quad;
            u16 tb[8];
            #pragma unroll
            for (int j = 0; j < 8; ++j) tb[j] = f2us(bf[8*c2 + j]);
            *(short8*)&Blds[(r >> 4) * 512 + lane8 * 8] = *(short8*)tb;
        }
        __syncthreads();

        short8 afr[4], bfr[4];
        #pragma unroll
        for (int i = 0; i < 4; ++i) afr[i] = *(const short8*)&Alds[(wy*4 + i) * 512 + l * 8];
        #pragma unroll
        for (int j = 0; j < 4; ++j) bfr[j] = *(const short8*)&Blds[(wx*4 + j) * 512 + l * 8];
        #pragma unroll
        for (int i = 0; i < 4; ++i)
            #pragma unroll
            for (int j = 0; j < 4; ++j)
                acc[i][j] = __builtin_amdgcn_mfma_f32_16x16x32_bf16(afr[i], bfr[j], acc[i][j], 0, 0, 0);
    }

    #pragma unroll
    for (int i = 0; i < 4; ++i)
        #pragma unroll
        for (int j = 0; j < 4; ++j) {
            const int nn = n0 + wx * 64 + j * 16 + (l & 15);
            const float bb_ = bo[nn];
            #pragma unroll
            for (int rg = 0; rg < 4; ++rg) {
                const int mm = m0 + wy * 64 + i * 16 + (l >> 4) * 4 + rg;
                out[(size_t)mm * HID + nn] = acc[i][j][rg] + bb_;
            }
        }
}

extern "C" void kernel_launch(void* const* d_in, const int* in_sizes, int n_in,
                              void* d_out, int out_size, void* d_ws, size_t ws_size,
                              hipStream_t stream)
{
    const float* hs    = (const float*)d_in[0];
    const float* mask  = (const float*)d_in[1];
    const float* Wq    = (const float*)d_in[2];
    const float* bq    = (const float*)d_in[3];
    const float* Wk    = (const float*)d_in[4];
    const float* bk    = (const float*)d_in[5];
    const float* Wv    = (const float*)d_in[6];
    const float* bv    = (const float*)d_in[7];
    const float* Wo    = (const float*)d_in[8];
    const float* bo    = (const float*)d_in[9];
    // d_in[10] = beta: cancels in the ConsMax max-shift.
    const float* gamma = (const float*)d_in[11];
    float* out = (float*)d_out;

    const size_t tsz = (size_t)B_ * NH * S_ * HD;   // 4,194,304 elems
    u16* q    = (u16*)d_ws;           // [0, 4M)
    u16* k    = q + tsz;              // [4M, 8M)
    u16* vT   = k + tsz;              // [8M, 12M)   V^T [B,NH,HD,S]
    u16* Wcat = vT + tsz;             // [12M, 15M)  3 bf16 weights
    u16* ctx0 = Wcat;                 // [12M, 14M)  alias Wq/Wk_bf (dead)
    u16* ctx1 = q;                    // [0, 2M)     alias q-b0 (dead after attn b0)

    cvt_w<<<dim3(1024, 3), 256, 0, stream>>>(Wq, Wk, Wv, Wcat);
    qkv_gemm<<<dim3(32, 24), 256, 0, stream>>>(hs, Wcat, bq, bk, bv, q, k, vT);
    attn2<<<dim3(32, 16), 256, 0, stream>>>(q, k, vT, mask, gamma, ctx0, 0);
    attn2<<<dim3(32, 16), 256, 0, stream>>>(q, k, vT, mask, gamma, ctx1, 1);
    out_gemm<<<dim3(32, 8), 256, 0, stream>>>(ctx0, ctx1, Wo, bo, out);
}

// Round 10
// 296.469 us; speedup vs baseline: 1.0755x; 1.0755x over previous
//
#include <hip/hip_runtime.h>

// ConsMaxAttention MI355X — ROUND 10: full-async GEMMs + dbuf attention.
// r9 (318 us): qkv_gemm 101 us (fp32 A staging: 2x bytes + VALU cvt),
// attention ~170 us (2 barriers/tile, global latency exposed, 2 blk/CU),
// out_gemm 256 blocks = 1 blk/CU.
// Changes: (1) hs pre-converted to bf16 into d_out[0..8MB) (dead scratch
// until out_gemm); qkv_gemm stages A AND B via global_load_lds width=16 in
// fragment order (m97 structure). (2) attention: K/V double-buffered async
// into unpadded frag-order LDS, ONE barrier/iter, tile kt+1 + mask issued
// before compute on kt. (3) out_gemm 128x64 tiles -> 512 blocks, A async.
// ws 31.2 MB: q|k|vT 25.2 + Wcat3 6; ctx0 aliases Wcat (dead after qkv),
// ctx1 aliases q-b0 (attn launches serial per batch).

typedef unsigned short u16;
typedef __attribute__((ext_vector_type(8))) short short8;
typedef __attribute__((ext_vector_type(4))) float floatx4;

constexpr int B_  = 2;
constexpr int S_  = 2048;
constexpr int HID = 1024;
constexpr int NH  = 16;
constexpr int HD  = 64;
constexpr int M_  = B_ * S_;   // 4096

__device__ __forceinline__ float us2f(u16 u) {
    union { unsigned int i; float f; } x;
    x.i = ((unsigned int)u) << 16;
    return x.f;
}
__device__ __forceinline__ u16 f2us(float f) {
    union { float f; unsigned int i; } x;
    x.f = f;
    unsigned int r = x.i + 0x7FFFu + ((x.i >> 16) & 1u);  // RNE
    return (u16)(r >> 16);
}
__device__ __forceinline__ void async_lds16(const u16* g, u16* l) {
    __builtin_amdgcn_global_load_lds(
        (const __attribute__((address_space(1))) unsigned int*)g,
        (__attribute__((address_space(3))) unsigned int*)l, 16, 0, 0);
}

// ---------------------------------------------------------------------------
// Convert hs + Wq/Wk/Wv fp32 -> bf16. hs_bf lives in d_out scratch.
__global__ __launch_bounds__(256)
void cvt_all(const float* __restrict__ hs, const float* __restrict__ Wq,
             const float* __restrict__ Wk, const float* __restrict__ Wv,
             u16* __restrict__ hs_bf, u16* __restrict__ Wcat)
{
    const int bid = blockIdx.x;               // 0..7167
    const float* src;
    u16* dst;
    size_t base;
    if (bid < 4096) {                         // hs: 4,194,304 elems
        src = hs; dst = hs_bf; base = (size_t)bid * 1024;
    } else {
        const int s = (bid - 4096) >> 10;     // 0..2
        src = (s == 0) ? Wq : (s == 1) ? Wk : Wv;
        dst = Wcat + (size_t)s * 1048576;
        base = (size_t)((bid - 4096) & 1023) * 1024;
    }
    const size_t i = base + threadIdx.x * 4;
    float4 t = *(const float4*)(src + i);
    ushort4 o = { f2us(t.x), f2us(t.y), f2us(t.z), f2us(t.w) };
    *(ushort4*)(dst + i) = o;
}

// ---------------------------------------------------------------------------
// QKV GEMM, m97 structure: both operands bf16, async frag-order staging.
// p==2 writes V^T [B,NH,HD,S].
__global__ __launch_bounds__(256)
void qkv_gemm(const u16* __restrict__ hs_bf, const u16* __restrict__ Wcat,
              const float* __restrict__ bq, const float* __restrict__ bk,
              const float* __restrict__ bv,
              u16* __restrict__ Qo, u16* __restrict__ Ko, u16* __restrict__ VT)
{
    __shared__ u16 Alds[4096];    // 128x32, frag order: subtile s -> s*512 + l*8
    __shared__ u16 Blds[4096];

    const int tid = threadIdx.x;
    const int m0  = blockIdx.x * 128;
    const int n0g = blockIdx.y * 128;
    const int p   = n0g >> 10;
    const int n0  = n0g & 1023;
    const u16*   Wb = Wcat + (size_t)p * 1048576;
    const float* bi = (p == 0) ? bq : (p == 1) ? bk : bv;

    const int w = tid >> 6, l = tid & 63;
    const int quad = l >> 4, l16 = l & 15;
    const int wy = w >> 1, wx = w & 1;

    floatx4 acc[4][4];
    #pragma unroll
    for (int i = 0; i < 4; ++i)
        #pragma unroll
        for (int j = 0; j < 4; ++j) acc[i][j] = (floatx4){0.f, 0.f, 0.f, 0.f};

    for (int k0 = 0; k0 < HID; k0 += 32) {
        __syncthreads();                       // prev MFMAs done reading LDS
        #pragma unroll
        for (int c = 0; c < 2; ++c) {          // wave w stages subtiles 2w,2w+1
            const int s = w * 2 + c;
            async_lds16(hs_bf + (size_t)(m0 + s * 16 + l16) * HID + k0 + quad * 8,
                        &Alds[s * 512]);
            async_lds16(Wb + (size_t)(n0 + s * 16 + l16) * HID + k0 + quad * 8,
                        &Blds[s * 512]);
        }
        __syncthreads();                       // drain own vmcnt -> tiles ready

        short8 afr[4], bfr[4];
        #pragma unroll
        for (int i = 0; i < 4; ++i) afr[i] = *(const short8*)&Alds[(wy*4 + i) * 512 + l * 8];
        #pragma unroll
        for (int j = 0; j < 4; ++j) bfr[j] = *(const short8*)&Blds[(wx*4 + j) * 512 + l * 8];
        #pragma unroll
        for (int i = 0; i < 4; ++i)
            #pragma unroll
            for (int j = 0; j < 4; ++j)
                acc[i][j] = __builtin_amdgcn_mfma_f32_16x16x32_bf16(afr[i], bfr[j], acc[i][j], 0, 0, 0);
    }

    #pragma unroll
    for (int i = 0; i < 4; ++i)
        #pragma unroll
        for (int j = 0; j < 4; ++j) {
            const int nn   = n0 + wx * 64 + j * 16 + l16;
            const int head = nn >> 6, dd = nn & 63;
            const float bb_ = bi[nn];
            const int mmb = m0 + wy * 64 + i * 16 + quad * 4;
            const int b = mmb >> 11, ss = mmb & (S_ - 1);
            if (p == 2) {                      // V^T: 4 contiguous s
                ushort4 st;
                st.x = f2us(acc[i][j][0] + bb_);
                st.y = f2us(acc[i][j][1] + bb_);
                st.z = f2us(acc[i][j][2] + bb_);
                st.w = f2us(acc[i][j][3] + bb_);
                *(ushort4*)(VT + (((size_t)(b * NH + head)) * HD + dd) * S_ + ss) = st;
            } else {
                u16* Out = (p == 0) ? Qo : Ko;
                #pragma unroll
                for (int rg = 0; rg < 4; ++rg)
                    Out[(((size_t)b * NH + head) * S_ + ss + rg) * HD + dd] =
                        f2us(acc[i][j][rg] + bb_);
            }
        }
}

// ---------------------------------------------------------------------------
// Stage one 64-key K/V tile (frag order, async). 4 waves x 2 chunks each.
__device__ __forceinline__ void stage_kv(const u16* Kbg, const u16* Vbg, int kt,
                                         u16* Kd, u16* Vd, int w, int l16, int quad)
{
    #pragma unroll
    for (int c = 0; c < 2; ++c) {
        const int ch = w + 4 * c;              // 0..7
        const int s = ch & 3, t = ch >> 2;
        async_lds16(Kbg + ((size_t)kt * 64 + s * 16 + l16) * HD + t * 32 + quad * 8,
                    Kd + s * 1024 + t * 512);
        async_lds16(Vbg + (size_t)(s * 16 + l16) * S_ + kt * 64 + t * 32 + quad * 8,
                    Vd + s * 1024 + t * 512);
    }
}

// Flash ConsMax attention, S^T form, double-buffered async K/V, 1 barrier/iter.
__global__ __launch_bounds__(256)
void attn3(const u16* __restrict__ Qg, const u16* __restrict__ Kg,
           const u16* __restrict__ VTg, const float* __restrict__ mask,
           const float* __restrict__ gamma, u16* __restrict__ ctx, int b0)
{
    __shared__ u16 Kb[2][4096];    // frag order: key-subtile s, t, lane*8
    __shared__ u16 Vb[2][4096];    // frag order: d-subtile jn, t, lane*8
    __shared__ u16 Pl[4][1024];    // per-wave P [16q][64key] in A-frag order
    __shared__ float maskb[2][64];

    const int tid = threadIdx.x;
    const int w = tid >> 6, l = tid & 63;
    const int quad = l >> 4, l16 = l & 15;
    const int qb = blockIdx.x;
    const int h  = blockIdx.y;
    const int bh = b0 * NH + h;

    const u16* Qb  = Qg  + (size_t)bh * S_ * HD;
    const u16* Kbg = Kg  + (size_t)bh * S_ * HD;
    const u16* Vbg = VTg + (size_t)bh * HD * S_;

    short8 qf[2];                  // B-frag of Q^T: q = qb*64+16w+l16
    #pragma unroll
    for (int t = 0; t < 2; ++t)
        qf[t] = *(const short8*)(Qb + ((size_t)qb * 64 + 16 * w + l16) * HD + 32 * t + quad * 8);

    floatx4 o_acc[4];
    #pragma unroll
    for (int jn = 0; jn < 4; ++jn) o_acc[jn] = (floatx4){0.f, 0.f, 0.f, 0.f};
    float m_run = -1e30f;          // online max for q = l16

    stage_kv(Kbg, Vbg, 0, Kb[0], Vb[0], w, l16, quad);
    if (tid < 64) maskb[0][tid] = (1.0f - mask[(size_t)b0 * S_ + tid]) * -10000.0f;
    __syncthreads();               // drains this wave's asyncs too

    for (int kt = 0; kt < S_ / 64; ++kt) {
        const int cb = kt & 1, nb = cb ^ 1;
        float mnext = 0.0f;
        if (kt < 31) {
            stage_kv(Kbg, Vbg, kt + 1, Kb[nb], Vb[nb], w, l16, quad);
            if (tid < 64)
                mnext = (1.0f - mask[(size_t)b0 * S_ + (kt + 1) * 64 + tid]) * -10000.0f;
        }

        // S^T = K·Q^T : D[m=key][n=q=l16]
        floatx4 st4[4];
        #pragma unroll
        for (int j = 0; j < 4; ++j) st4[j] = (floatx4){0.f, 0.f, 0.f, 0.f};
        #pragma unroll
        for (int t = 0; t < 2; ++t)
            #pragma unroll
            for (int j = 0; j < 4; ++j) {
                short8 kf = *(const short8*)&Kb[cb][j * 1024 + t * 512 + l * 8];
                st4[j] = __builtin_amdgcn_mfma_f32_16x16x32_bf16(kf, qf[t], st4[j], 0, 0, 0);
            }

        float sv[4][4], mx = -1e30f;
        #pragma unroll
        for (int j = 0; j < 4; ++j)
            #pragma unroll
            for (int i = 0; i < 4; ++i) {
                const float s = st4[j][i] * 0.125f + maskb[cb][j * 16 + quad * 4 + i];
                sv[j][i] = s;
                mx = fmaxf(mx, s);
            }
        mx = fmaxf(mx, __shfl_xor(mx, 16, 64));
        mx = fmaxf(mx, __shfl_xor(mx, 32, 64));

        const float nm  = fmaxf(m_run, mx);
        const float scl = __expf(m_run - nm);
        m_run = nm;

        // P -> wave-private LDS in PV A-frag order; writer holds q=l16,
        // keys kb..kb+3 with kb = j*16 + quad*4.
        #pragma unroll
        for (int j = 0; j < 4; ++j) {
            ushort4 pp;
            pp.x = f2us(__expf(sv[j][0] - nm));
            pp.y = f2us(__expf(sv[j][1] - nm));
            pp.z = f2us(__expf(sv[j][2] - nm));
            pp.w = f2us(__expf(sv[j][3] - nm));
            const int off = (j >> 1) * 512 + ((j * 2 + (quad >> 1)) & 3) * 128
                          + l16 * 8 + (quad & 1) * 4;
            *(ushort4*)&Pl[w][off] = pp;
        }

        // rescale O (rows q = quad*4+i use lane quad*4+i's scale)
        #pragma unroll
        for (int i = 0; i < 4; ++i) {
            const float si = __shfl(scl, quad * 4 + i, 64);
            #pragma unroll
            for (int jn = 0; jn < 4; ++jn) o_acc[jn][i] *= si;
        }

        // O += P·V
        #pragma unroll
        for (int t = 0; t < 2; ++t) {
            short8 pf = *(const short8*)&Pl[w][t * 512 + l * 8];
            #pragma unroll
            for (int jn = 0; jn < 4; ++jn) {
                short8 vf = *(const short8*)&Vb[cb][jn * 1024 + t * 512 + l * 8];
                o_acc[jn] = __builtin_amdgcn_mfma_f32_16x16x32_bf16(pf, vf, o_acc[jn], 0, 0, 0);
            }
        }

        if (kt < 31 && tid < 64) maskb[nb][tid] = mnext;
        __syncthreads();           // all waves done with cb; nb asyncs drained
    }

    const float ig = 1.0f / gamma[0];
    #pragma unroll
    for (int jn = 0; jn < 4; ++jn)
        #pragma unroll
        for (int i = 0; i < 4; ++i) {
            const int srow = qb * 64 + 16 * w + quad * 4 + i;
            ctx[(size_t)srow * HID + h * HD + jn * 16 + l16] = f2us(o_acc[jn][i] * ig);
        }
}

// ---------------------------------------------------------------------------
// Output GEMM: 128x64 tile (512 blocks). A = ctx bf16 async; B = Wo fp32
// (VALU cvt, frag-order); fp32 stores.
__global__ __launch_bounds__(256)
void out_gemm(const u16* __restrict__ ctx0, const u16* __restrict__ ctx1,
              const float* __restrict__ Wo, const float* __restrict__ bo,
              float* __restrict__ out)
{
    __shared__ u16 Alds[4096];     // 128x32
    __shared__ u16 Blds[2048];     // 64x32

    const int tid = threadIdx.x;
    const int m0 = blockIdx.x * 128;
    const int n0 = blockIdx.y * 64;
    const u16* ctxp = (m0 < S_) ? ctx0 : ctx1;
    const int mr0 = m0 & (S_ - 1);

    const int w = tid >> 6, l = tid & 63;
    const int quad = l >> 4, l16 = l & 15;
    const int br = tid >> 2;       // B staging row 0..63
    const int bq_ = tid & 3;       // B staging k-chunk

    floatx4 acc[2][4];
    #pragma unroll
    for (int i = 0; i < 2; ++i)
        #pragma unroll
        for (int j = 0; j < 4; ++j) acc[i][j] = (floatx4){0.f, 0.f, 0.f, 0.f};

    for (int k0 = 0; k0 < HID; k0 += 32) {
        const float* Bp = Wo + (size_t)(n0 + br) * HID + k0 + bq_ * 8;
        float bf8[8];
        #pragma unroll
        for (int c = 0; c < 2; ++c) {
            float4 u = *(const float4*)(Bp + 4 * c);
            bf8[4*c] = u.x; bf8[4*c+1] = u.y; bf8[4*c+2] = u.z; bf8[4*c+3] = u.w;
        }
        __syncthreads();
        #pragma unroll
        for (int c = 0; c < 2; ++c) {          // A async: wave w -> 2w, 2w+1
            const int s = w * 2 + c;
            async_lds16(ctxp + (size_t)(mr0 + s * 16 + l16) * HID + k0 + quad * 8,
                        &Alds[s * 512]);
        }
        {                                       // B frag-order VALU write
            u16 tb[8];
            #pragma unroll
            for (int j = 0; j < 8; ++j) tb[j] = f2us(bf8[j]);
            *(short8*)&Blds[(br >> 4) * 512 + (bq_ * 16 + (br & 15)) * 8] = *(short8*)tb;
        }
        __syncthreads();

        short8 afr[2], bfr[4];
        #pragma unroll
        for (int i = 0; i < 2; ++i) afr[i] = *(const short8*)&Alds[(w*2 + i) * 512 + l * 8];
        #pragma unroll
        for (int j = 0; j < 4; ++j) bfr[j] = *(const short8*)&Blds[j * 512 + l * 8];
        #pragma unroll
        for (int i = 0; i < 2; ++i)
            #pragma unroll
            for (int j = 0; j < 4; ++j)
                acc[i][j] = __builtin_amdgcn_mfma_f32_16x16x32_bf16(afr[i], bfr[j], acc[i][j], 0, 0, 0);
    }

    #pragma unroll
    for (int i = 0; i < 2; ++i)
        #pragma unroll
        for (int j = 0; j < 4; ++j) {
            const int nn = n0 + j * 16 + l16;
            const float bb_ = bo[nn];
            #pragma unroll
            for (int rg = 0; rg < 4; ++rg) {
                const int mm = m0 + w * 32 + i * 16 + quad * 4 + rg;
                out[(size_t)mm * HID + nn] = acc[i][j][rg] + bb_;
            }
        }
}

extern "C" void kernel_launch(void* const* d_in, const int* in_sizes, int n_in,
                              void* d_out, int out_size, void* d_ws, size_t ws_size,
                              hipStream_t stream)
{
    const float* hs    = (const float*)d_in[0];
    const float* mask  = (const float*)d_in[1];
    const float* Wq    = (const float*)d_in[2];
    const float* bq    = (const float*)d_in[3];
    const float* Wk    = (const float*)d_in[4];
    const float* bk    = (const float*)d_in[5];
    const float* Wv    = (const float*)d_in[6];
    const float* bv    = (const float*)d_in[7];
    const float* Wo    = (const float*)d_in[8];
    const float* bo    = (const float*)d_in[9];
    // d_in[10] = beta: cancels in the ConsMax max-shift.
    const float* gamma = (const float*)d_in[11];
    float* out = (float*)d_out;

    const size_t tsz = (size_t)B_ * NH * S_ * HD;   // 4,194,304 elems
    u16* q     = (u16*)d_ws;           // [0, 8.4MB)
    u16* k     = q + tsz;              // [8.4, 16.8)
    u16* vT    = k + tsz;              // [16.8, 25.2)  V^T [B,NH,HD,S]
    u16* Wcat  = vT + tsz;             // [25.2, 31.5)  3 bf16 weights
    u16* hs_bf = (u16*)d_out;          // d_out scratch (dead before out_gemm)
    u16* ctx0  = Wcat;                 // alias Wcat (dead after qkv_gemm)
    u16* ctx1  = q;                    // alias q-b0 (dead after attn b0)

    cvt_all<<<dim3(7168), 256, 0, stream>>>(hs, Wq, Wk, Wv, hs_bf, Wcat);
    qkv_gemm<<<dim3(32, 24), 256, 0, stream>>>(hs_bf, Wcat, bq, bk, bv, q, k, vT);
    attn3<<<dim3(32, 16), 256, 0, stream>>>(q, k, vT, mask, gamma, ctx0, 0);
    attn3<<<dim3(32, 16), 256, 0, stream>>>(q, k, vT, mask, gamma, ctx1, 1);
    out_gemm<<<dim3(32, 16), 256, 0, stream>>>(ctx0, ctx1, Wo, bo, out);
}

// Round 11
// 281.666 us; speedup vs baseline: 1.1320x; 1.0526x over previous
//
#include <hip/hip_runtime.h>

// ConsMaxAttention MI355X — ROUND 11: double BK everywhere (amortize the
// barrier drain). r10 (296 us): qkv 71 us @ MfmaUtil 13%, VALUBusy 9% —
// latency-bound on 2 barrier drains per 16 MFMAs. Changes:
//  (1) qkv_gemm BK=64: 16 iters x 32 MFMA, 8 asyncs/lane/iter, LDS 32 KB.
//  (2) attention 128-key tiles: 16 iters x 32 MFMA, LDS 48.5 KB; dbuf
//      removed (r10 proved it neutral — the m99/m100 lesson).
//  (3) out_gemm BK=64 with BOTH operands async (Wo pre-converted bf16).
// ws = exactly 32 MiB (r3-proven): q|k|vT 24M + Wcat 6M + Wo_bf 2M;
// ctx0 aliases Wcat (dead after qkv), ctx1 aliases q-b0 (attn serial).

typedef unsigned short u16;
typedef __attribute__((ext_vector_type(8))) short short8;
typedef __attribute__((ext_vector_type(4))) float floatx4;

constexpr int B_  = 2;
constexpr int S_  = 2048;
constexpr int HID = 1024;
constexpr int NH  = 16;
constexpr int HD  = 64;
constexpr int M_  = B_ * S_;   // 4096

__device__ __forceinline__ float us2f(u16 u) {
    union { unsigned int i; float f; } x;
    x.i = ((unsigned int)u) << 16;
    return x.f;
}
__device__ __forceinline__ u16 f2us(float f) {
    union { float f; unsigned int i; } x;
    x.f = f;
    unsigned int r = x.i + 0x7FFFu + ((x.i >> 16) & 1u);  // RNE
    return (u16)(r >> 16);
}
__device__ __forceinline__ void async_lds16(const u16* g, u16* l) {
    __builtin_amdgcn_global_load_lds(
        (const __attribute__((address_space(1))) unsigned int*)g,
        (__attribute__((address_space(3))) unsigned int*)l, 16, 0, 0);
}

// ---------------------------------------------------------------------------
// Convert hs, Wq, Wk, Wv, Wo fp32 -> bf16. hs_bf in d_out scratch.
__global__ __launch_bounds__(256)
void cvt_all(const float* __restrict__ hs, const float* __restrict__ Wq,
             const float* __restrict__ Wk, const float* __restrict__ Wv,
             const float* __restrict__ Wo,
             u16* __restrict__ hs_bf, u16* __restrict__ Wcat,
             u16* __restrict__ Wo_bf)
{
    const int bid = blockIdx.x;               // 0..8191
    const float* src;
    u16* dst;
    size_t base;
    if (bid < 4096) {                         // hs
        src = hs; dst = hs_bf; base = (size_t)bid * 1024;
    } else if (bid < 7168) {                  // Wq/Wk/Wv
        const int s = (bid - 4096) >> 10;
        src = (s == 0) ? Wq : (s == 1) ? Wk : Wv;
        dst = Wcat + (size_t)s * 1048576;
        base = (size_t)((bid - 4096) & 1023) * 1024;
    } else {                                  // Wo
        src = Wo; dst = Wo_bf; base = (size_t)(bid - 7168) * 1024;
    }
    const size_t i = base + threadIdx.x * 4;
    float4 t = *(const float4*)(src + i);
    ushort4 o = { f2us(t.x), f2us(t.y), f2us(t.z), f2us(t.w) };
    *(ushort4*)(dst + i) = o;
}

// ---------------------------------------------------------------------------
// QKV GEMM: 128x128 tile, BK=64, both operands async frag-order.
// LDS chunk: subtile s (16 rows) x k-half t (32) -> s*1024 + t*512 + lane*8.
__global__ __launch_bounds__(256)
void qkv_gemm(const u16* __restrict__ hs_bf, const u16* __restrict__ Wcat,
              const float* __restrict__ bq, const float* __restrict__ bk,
              const float* __restrict__ bv,
              u16* __restrict__ Qo, u16* __restrict__ Ko, u16* __restrict__ VT)
{
    __shared__ u16 Alds[8192];    // 128 x 64
    __shared__ u16 Blds[8192];

    const int tid = threadIdx.x;
    const int m0  = blockIdx.x * 128;
    const int n0g = blockIdx.y * 128;
    const int p   = n0g >> 10;
    const int n0  = n0g & 1023;
    const u16*   Wb = Wcat + (size_t)p * 1048576;
    const float* bi = (p == 0) ? bq : (p == 1) ? bk : bv;

    const int w = tid >> 6, l = tid & 63;
    const int quad = l >> 4, l16 = l & 15;
    const int wy = w >> 1, wx = w & 1;

    floatx4 acc[4][4];
    #pragma unroll
    for (int i = 0; i < 4; ++i)
        #pragma unroll
        for (int j = 0; j < 4; ++j) acc[i][j] = (floatx4){0.f, 0.f, 0.f, 0.f};

    for (int k0 = 0; k0 < HID; k0 += 64) {
        __syncthreads();
        #pragma unroll
        for (int c = 0; c < 2; ++c) {         // wave w: subtiles 2w, 2w+1
            const int s = w * 2 + c;
            #pragma unroll
            for (int t = 0; t < 2; ++t) {
                async_lds16(hs_bf + (size_t)(m0 + s * 16 + l16) * HID + k0 + t * 32 + quad * 8,
                            &Alds[s * 1024 + t * 512]);
                async_lds16(Wb + (size_t)(n0 + s * 16 + l16) * HID + k0 + t * 32 + quad * 8,
                            &Blds[s * 1024 + t * 512]);
            }
        }
        __syncthreads();

        #pragma unroll
        for (int t = 0; t < 2; ++t) {
            short8 afr[4], bfr[4];
            #pragma unroll
            for (int i = 0; i < 4; ++i)
                afr[i] = *(const short8*)&Alds[(wy*4 + i) * 1024 + t * 512 + l * 8];
            #pragma unroll
            for (int j = 0; j < 4; ++j)
                bfr[j] = *(const short8*)&Blds[(wx*4 + j) * 1024 + t * 512 + l * 8];
            #pragma unroll
            for (int i = 0; i < 4; ++i)
                #pragma unroll
                for (int j = 0; j < 4; ++j)
                    acc[i][j] = __builtin_amdgcn_mfma_f32_16x16x32_bf16(afr[i], bfr[j], acc[i][j], 0, 0, 0);
        }
    }

    #pragma unroll
    for (int i = 0; i < 4; ++i)
        #pragma unroll
        for (int j = 0; j < 4; ++j) {
            const int nn   = n0 + wx * 64 + j * 16 + l16;
            const int head = nn >> 6, dd = nn & 63;
            const float bb_ = bi[nn];
            const int mmb = m0 + wy * 64 + i * 16 + quad * 4;
            const int b = mmb >> 11, ss = mmb & (S_ - 1);
            if (p == 2) {                      // V^T [B,NH,HD,S]
                ushort4 st;
                st.x = f2us(acc[i][j][0] + bb_);
                st.y = f2us(acc[i][j][1] + bb_);
                st.z = f2us(acc[i][j][2] + bb_);
                st.w = f2us(acc[i][j][3] + bb_);
                *(ushort4*)(VT + (((size_t)(b * NH + head)) * HD + dd) * S_ + ss) = st;
            } else {
                u16* Out = (p == 0) ? Qo : Ko;
                #pragma unroll
                for (int rg = 0; rg < 4; ++rg)
                    Out[(((size_t)b * NH + head) * S_ + ss + rg) * HD + dd] =
                        f2us(acc[i][j][rg] + bb_);
            }
        }
}

// ---------------------------------------------------------------------------
// Flash ConsMax attention: 64 q/block, 128-key tiles, single-buffered async.
// S^T = K·Q^T keeps P key-contiguous; P in per-wave A-frag order.
__global__ __launch_bounds__(256)
void attn4(const u16* __restrict__ Qg, const u16* __restrict__ Kg,
           const u16* __restrict__ VTg, const float* __restrict__ mask,
           const float* __restrict__ gamma, u16* __restrict__ ctx, int b0)
{
    __shared__ u16 Kb[8192];      // 128 keys x 64 d, frag order (key-subtiles)
    __shared__ u16 Vb[8192];      // 64 d x 128 keys, B-frag order for PV
    __shared__ u16 Pl[4][2048];   // per-wave [16 q][128 key], A-frag order
    __shared__ float maskb[128];

    const int tid = threadIdx.x;
    const int w = tid >> 6, l = tid & 63;
    const int quad = l >> 4, l16 = l & 15;
    const int qb = blockIdx.x;
    const int h  = blockIdx.y;
    const int bh = b0 * NH + h;

    const u16* Qb  = Qg  + (size_t)bh * S_ * HD;
    const u16* Kbg = Kg  + (size_t)bh * S_ * HD;
    const u16* Vbg = VTg + (size_t)bh * HD * S_;

    short8 qf[2];                 // B-frag of Q^T: q = qb*64 + 16w + l16
    #pragma unroll
    for (int t = 0; t < 2; ++t)
        qf[t] = *(const short8*)(Qb + ((size_t)qb * 64 + 16 * w + l16) * HD + 32 * t + quad * 8);

    floatx4 o_acc[4];
    #pragma unroll
    for (int jn = 0; jn < 4; ++jn) o_acc[jn] = (floatx4){0.f, 0.f, 0.f, 0.f};
    float m_run = -1e30f;         // online max for q = l16

    for (int kt = 0; kt < S_ / 128; ++kt) {
        float mnext = 0.0f;
        if (tid < 128)
            mnext = (1.0f - mask[(size_t)b0 * S_ + kt * 128 + tid]) * -10000.0f;
        __syncthreads();          // all waves done with previous tile
        #pragma unroll
        for (int c = 0; c < 2; ++c) {          // K: wave w -> key-subtiles 2w,2w+1
            const int s = w * 2 + c;
            #pragma unroll
            for (int t = 0; t < 2; ++t)
                async_lds16(Kbg + ((size_t)kt * 128 + s * 16 + l16) * HD + t * 32 + quad * 8,
                            &Kb[s * 1024 + t * 512]);
        }
        #pragma unroll
        for (int tt = 0; tt < 4; ++tt)         // V: wave w -> d-subtile w
            async_lds16(Vbg + (size_t)(w * 16 + l16) * S_ + kt * 128 + tt * 32 + quad * 8,
                        &Vb[w * 2048 + tt * 512]);
        if (tid < 128) maskb[tid] = mnext;
        __syncthreads();

        // S^T = K·Q^T : 128 keys x 16 q per wave (q = l16)
        floatx4 st4[8];
        #pragma unroll
        for (int j = 0; j < 8; ++j) st4[j] = (floatx4){0.f, 0.f, 0.f, 0.f};
        #pragma unroll
        for (int t = 0; t < 2; ++t)
            #pragma unroll
            for (int j = 0; j < 8; ++j) {
                short8 kf = *(const short8*)&Kb[j * 1024 + t * 512 + l * 8];
                st4[j] = __builtin_amdgcn_mfma_f32_16x16x32_bf16(kf, qf[t], st4[j], 0, 0, 0);
            }

        float mx = -1e30f;
        #pragma unroll
        for (int j = 0; j < 8; ++j)
            #pragma unroll
            for (int i = 0; i < 4; ++i) {
                st4[j][i] = st4[j][i] * 0.125f + maskb[j * 16 + quad * 4 + i];
                mx = fmaxf(mx, st4[j][i]);
            }
        mx = fmaxf(mx, __shfl_xor(mx, 16, 64));
        mx = fmaxf(mx, __shfl_xor(mx, 32, 64));

        const float nm  = fmaxf(m_run, mx);
        const float scl = __expf(m_run - nm);
        m_run = nm;

        // P -> wave-private LDS, A-frag order for PV. Writer: q=l16,
        // keys j*16 + quad*4 + i  (i=0..3 contiguous -> ushort4).
        #pragma unroll
        for (int j = 0; j < 8; ++j) {
            ushort4 pp;
            pp.x = f2us(__expf(st4[j][0] - nm));
            pp.y = f2us(__expf(st4[j][1] - nm));
            pp.z = f2us(__expf(st4[j][2] - nm));
            pp.w = f2us(__expf(st4[j][3] - nm));
            const int off = (j >> 1) * 512
                          + (l16 + 16 * ((j & 1) * 2 + (quad >> 1))) * 8
                          + (quad & 1) * 4;
            *(ushort4*)&Pl[w][off] = pp;
        }

        // rescale O (row q = quad*4+i uses lane quad*4+i's scale)
        #pragma unroll
        for (int i = 0; i < 4; ++i) {
            const float si = __shfl(scl, quad * 4 + i, 64);
            #pragma unroll
            for (int jn = 0; jn < 4; ++jn) o_acc[jn][i] *= si;
        }

        // O += P·V : 4 k-steps of 32 keys
        #pragma unroll
        for (int tt = 0; tt < 4; ++tt) {
            short8 pf = *(const short8*)&Pl[w][tt * 512 + l * 8];
            #pragma unroll
            for (int jn = 0; jn < 4; ++jn) {
                short8 vf = *(const short8*)&Vb[jn * 2048 + tt * 512 + l * 8];
                o_acc[jn] = __builtin_amdgcn_mfma_f32_16x16x32_bf16(pf, vf, o_acc[jn], 0, 0, 0);
            }
        }
    }

    const float ig = 1.0f / gamma[0];
    #pragma unroll
    for (int jn = 0; jn < 4; ++jn)
        #pragma unroll
        for (int i = 0; i < 4; ++i) {
            const int srow = qb * 64 + 16 * w + quad * 4 + i;
            ctx[(size_t)srow * HID + h * HD + jn * 16 + l16] = f2us(o_acc[jn][i] * ig);
        }
}

// ---------------------------------------------------------------------------
// Output GEMM: 128x64 tile, BK=64, both operands bf16 async. fp32 stores.
__global__ __launch_bounds__(256)
void out_gemm(const u16* __restrict__ ctx0, const u16* __restrict__ ctx1,
              const u16* __restrict__ Wo_bf, const float* __restrict__ bo,
              float* __restrict__ out)
{
    __shared__ u16 Alds[8192];     // 128 x 64
    __shared__ u16 Blds[4096];     // 64 x 64

    const int tid = threadIdx.x;
    const int m0 = blockIdx.x * 128;
    const int n0 = blockIdx.y * 64;
    const u16* ctxp = (m0 < S_) ? ctx0 : ctx1;
    const int mr0 = m0 & (S_ - 1);

    const int w = tid >> 6, l = tid & 63;
    const int quad = l >> 4, l16 = l & 15;

    floatx4 acc[2][4];
    #pragma unroll
    for (int i = 0; i < 2; ++i)
        #pragma unroll
        for (int j = 0; j < 4; ++j) acc[i][j] = (floatx4){0.f, 0.f, 0.f, 0.f};

    for (int k0 = 0; k0 < HID; k0 += 64) {
        __syncthreads();
        #pragma unroll
        for (int c = 0; c < 2; ++c) {          // A: wave w -> subtiles 2w, 2w+1
            const int s = w * 2 + c;
            #pragma unroll
            for (int t = 0; t < 2; ++t)
                async_lds16(ctxp + (size_t)(mr0 + s * 16 + l16) * HID + k0 + t * 32 + quad * 8,
                            &Alds[s * 1024 + t * 512]);
        }
        #pragma unroll
        for (int t = 0; t < 2; ++t)            // B: wave w -> n-subtile w
            async_lds16(Wo_bf + (size_t)(n0 + w * 16 + l16) * HID + k0 + t * 32 + quad * 8,
                        &Blds[w * 1024 + t * 512]);
        __syncthreads();

        #pragma unroll
        for (int t = 0; t < 2; ++t) {
            short8 afr[2], bfr[4];
            #pragma unroll
            for (int i = 0; i < 2; ++i)
                afr[i] = *(const short8*)&Alds[(w*2 + i) * 1024 + t * 512 + l * 8];
            #pragma unroll
            for (int j = 0; j < 4; ++j)
                bfr[j] = *(const short8*)&Blds[j * 1024 + t * 512 + l * 8];
            #pragma unroll
            for (int i = 0; i < 2; ++i)
                #pragma unroll
                for (int j = 0; j < 4; ++j)
                    acc[i][j] = __builtin_amdgcn_mfma_f32_16x16x32_bf16(afr[i], bfr[j], acc[i][j], 0, 0, 0);
        }
    }

    #pragma unroll
    for (int i = 0; i < 2; ++i)
        #pragma unroll
        for (int j = 0; j < 4; ++j) {
            const int nn = n0 + j * 16 + l16;
            const float bb_ = bo[nn];
            #pragma unroll
            for (int rg = 0; rg < 4; ++rg) {
                const int mm = m0 + w * 32 + i * 16 + quad * 4 + rg;
                out[(size_t)mm * HID + nn] = acc[i][j][rg] + bb_;
            }
        }
}

extern "C" void kernel_launch(void* const* d_in, const int* in_sizes, int n_in,
                              void* d_out, int out_size, void* d_ws, size_t ws_size,
                              hipStream_t stream)
{
    const float* hs    = (const float*)d_in[0];
    const float* mask  = (const float*)d_in[1];
    const float* Wq    = (const float*)d_in[2];
    const float* bq    = (const float*)d_in[3];
    const float* Wk    = (const float*)d_in[4];
    const float* bk    = (const float*)d_in[5];
    const float* Wv    = (const float*)d_in[6];
    const float* bv    = (const float*)d_in[7];
    const float* Wo    = (const float*)d_in[8];
    const float* bo    = (const float*)d_in[9];
    // d_in[10] = beta: cancels in the ConsMax max-shift.
    const float* gamma = (const float*)d_in[11];
    float* out = (float*)d_out;

    const size_t tsz = (size_t)B_ * NH * S_ * HD;   // 4,194,304 elems
    u16* q     = (u16*)d_ws;           // [0,    8.4M)
    u16* k     = q + tsz;              // [8.4,  16.8)
    u16* vT    = k + tsz;              // [16.8, 25.2)  V^T [B,NH,HD,S]
    u16* Wcat  = vT + tsz;             // [25.2, 31.5)
    u16* Wo_bf = Wcat + 3u * 1048576u; // [31.5, 33.6)  -> total 32 MiB exactly
    u16* hs_bf = (u16*)d_out;          // d_out scratch (dead before out_gemm)
    u16* ctx0  = Wcat;                 // alias Wq/Wk_bf (dead after qkv_gemm)
    u16* ctx1  = q;                    // alias q-b0 (dead after attn b0)

    cvt_all<<<dim3(8192), 256, 0, stream>>>(hs, Wq, Wk, Wv, Wo, hs_bf, Wcat, Wo_bf);
    qkv_gemm<<<dim3(32, 24), 256, 0, stream>>>(hs_bf, Wcat, bq, bk, bv, q, k, vT);
    attn4<<<dim3(32, 16), 256, 0, stream>>>(q, k, vT, mask, gamma, ctx0, 0);
    attn4<<<dim3(32, 16), 256, 0, stream>>>(q, k, vT, mask, gamma, ctx1, 1);
    out_gemm<<<dim3(32, 16), 256, 0, stream>>>(ctx0, ctx1, Wo_bf, bo, out);
}